// Round 1
// baseline (137.771 us; speedup 1.0000x reference)
//
#include <hip/hip_runtime.h>

#define B_N 16
#define C_N 3
#define H_N 512
#define W_N 512
#define PLANES (B_N * C_N)            // 48
#define ROWS_PER_BLOCK 32
#define CHUNKS (H_N / ROWS_PER_BLOCK) // 16
#define NBLK (PLANES * CHUNKS)        // 768
#define STATS3 (W_N * 3)              // 1536
#define SCALE (-1.0f / 8192.0f)       // -1/(B*H) == -1/(B*W), weights all 1
#define EPS_F 1e-12f

// K1: single streaming pass, reads x and ref exactly once.
//  - Row terms: each wave owns whole rows (64 lanes x 8 floats = 512).
//    Row partial sums are kept in registers (24 values) and reduced in ONE
//    batched 6-step butterfly AFTER the load loop (24 independent shfl
//    chains instead of 8 serial 6-deep chains interleaved with the loads).
//  - Column partials: each lane owns 8 fixed columns, register-accumulated,
//    LDS-combined across the block's 4 waves, then PLAIN coalesced stores to
//    colpart[block][1536] (no atomics — deterministic).
//  - Block 0 additionally zeroes the K2 completion counter (workspace is
//    poisoned by the harness every iteration, so it must be re-zeroed here).
__global__ __launch_bounds__(256) void spl_main_kernel(
    const float* __restrict__ x, const float* __restrict__ r,
    float* __restrict__ colpart, float* __restrict__ rowpart,
    unsigned int* __restrict__ counter) {
    if (blockIdx.x == 0 && threadIdx.x == 0)
        __hip_atomic_store(counter, 0u, __ATOMIC_RELAXED, __HIP_MEMORY_SCOPE_AGENT);

    const int p     = blockIdx.x / CHUNKS;
    const int chunk = blockIdx.x % CHUNKS;
    const int wave  = threadIdx.x >> 6;
    const int lane  = threadIdx.x & 63;

    const float* xp = x + (size_t)p * (H_N * W_N);
    const float* rp = r + (size_t)p * (H_N * W_N);

    float cxx[8] = {0, 0, 0, 0, 0, 0, 0, 0};
    float crr[8] = {0, 0, 0, 0, 0, 0, 0, 0};
    float cxr[8] = {0, 0, 0, 0, 0, 0, 0, 0};
    float rsxx[8], rsrr[8], rsxr[8];  // per-row, per-lane partials

    const int r0 = chunk * ROWS_PER_BLOCK;
    #pragma unroll
    for (int j = 0; j < ROWS_PER_BLOCK / 4; ++j) {
        const int row = r0 + wave + 4 * j;
        const float4* xr4 = (const float4*)(xp + (size_t)row * W_N);
        const float4* rr4 = (const float4*)(rp + (size_t)row * W_N);
        const float4 xa = xr4[lane];
        const float4 xb = xr4[lane + 64];
        const float4 ra = rr4[lane];
        const float4 rb = rr4[lane + 64];

        cxx[0] += xa.x * xa.x; cxx[1] += xa.y * xa.y; cxx[2] += xa.z * xa.z; cxx[3] += xa.w * xa.w;
        cxx[4] += xb.x * xb.x; cxx[5] += xb.y * xb.y; cxx[6] += xb.z * xb.z; cxx[7] += xb.w * xb.w;
        crr[0] += ra.x * ra.x; crr[1] += ra.y * ra.y; crr[2] += ra.z * ra.z; crr[3] += ra.w * ra.w;
        crr[4] += rb.x * rb.x; crr[5] += rb.y * rb.y; crr[6] += rb.z * rb.z; crr[7] += rb.w * rb.w;
        cxr[0] += xa.x * ra.x; cxr[1] += xa.y * ra.y; cxr[2] += xa.z * ra.z; cxr[3] += xa.w * ra.w;
        cxr[4] += xb.x * rb.x; cxr[5] += xb.y * rb.y; cxr[6] += xb.z * rb.z; cxr[7] += xb.w * rb.w;

        // per-row per-lane partials (same summation order as before)
        rsxx[j] = xa.x * xa.x + xa.y * xa.y + xa.z * xa.z + xa.w * xa.w
                + xb.x * xb.x + xb.y * xb.y + xb.z * xb.z + xb.w * xb.w;
        rsrr[j] = ra.x * ra.x + ra.y * ra.y + ra.z * ra.z + ra.w * ra.w
                + rb.x * rb.x + rb.y * rb.y + rb.z * rb.z + rb.w * rb.w;
        rsxr[j] = xa.x * ra.x + xa.y * ra.y + xa.z * ra.z + xa.w * ra.w
                + xb.x * rb.x + xb.y * rb.y + xb.z * rb.z + xb.w * rb.w;
    }

    // Batched butterfly: 24 independent chains, 6 steps. Static indexing only.
    #pragma unroll
    for (int m = 32; m > 0; m >>= 1) {
        #pragma unroll
        for (int j = 0; j < 8; ++j) {
            rsxx[j] += __shfl_down(rsxx[j], m, 64);
            rsrr[j] += __shfl_down(rsrr[j], m, 64);
            rsxr[j] += __shfl_down(rsxr[j], m, 64);
        }
    }
    float rowacc = 0.0f;  // valid on lane 0
    if (lane == 0) {
        #pragma unroll
        for (int j = 0; j < 8; ++j) {
            const float nx = fmaxf(sqrtf(rsxx[j]), EPS_F);
            const float nr = fmaxf(sqrtf(rsrr[j]), EPS_F);
            rowacc += rsxr[j] / (nx * nr);
        }
    }

    // combine column partials across the block's 4 waves via LDS
    __shared__ float smem[4][STATS3];  // 24 KiB
    #pragma unroll
    for (int k = 0; k < 4; ++k) {
        const int c0 = 4 * lane + k;
        const int c1 = c0 + 256;
        smem[wave][c0 * 3 + 0] = cxx[k];
        smem[wave][c0 * 3 + 1] = crr[k];
        smem[wave][c0 * 3 + 2] = cxr[k];
        smem[wave][c1 * 3 + 0] = cxx[4 + k];
        smem[wave][c1 * 3 + 1] = crr[4 + k];
        smem[wave][c1 * 3 + 2] = cxr[4 + k];
    }
    __shared__ float rowsums[4];
    if (lane == 0) rowsums[wave] = rowacc;
    __syncthreads();

    float* cp = colpart + (size_t)blockIdx.x * STATS3;
    #pragma unroll
    for (int k = 0; k < 6; ++k) {
        const int e = threadIdx.x + 256 * k;
        cp[e] = smem[0][e] + smem[1][e] + smem[2][e] + smem[3][e];
    }
    if (threadIdx.x == 0)
        rowpart[blockIdx.x] = rowsums[0] + rowsums[1] + rowsums[2] + rowsums[3];
}

// K2 (fused with old K3): one block per plane — reduce the 16 chunk partials,
// form the 512 column cosine terms, add the 16 row partial sums, publish
// planesum[p] with device scope. The LAST block to finish (atomic counter)
// folds the 48 plane scalars with the exact same 64-lane tree the old K3
// used and writes the output — bitwise-identical result, one fewer launch.
__global__ __launch_bounds__(256) void spl_reduce_kernel(
    const float* __restrict__ colpart, const float* __restrict__ rowpart,
    float* __restrict__ planesum, unsigned int* __restrict__ counter,
    float* __restrict__ out) {
    const int p = blockIdx.x;
    float acc[6] = {0, 0, 0, 0, 0, 0};
    const float* base = colpart + (size_t)p * CHUNKS * STATS3;
    #pragma unroll 4
    for (int c = 0; c < CHUNKS; ++c) {
        const float* bc = base + c * STATS3;
        #pragma unroll
        for (int k = 0; k < 6; ++k) acc[k] += bc[threadIdx.x + 256 * k];
    }
    __shared__ float sums[STATS3];
    #pragma unroll
    for (int k = 0; k < 6; ++k) sums[threadIdx.x + 256 * k] = acc[k];
    __syncthreads();

    float term = 0.0f;
    #pragma unroll
    for (int k = 0; k < 2; ++k) {
        const int col = threadIdx.x + 256 * k;
        const float sxx = sums[col * 3 + 0];
        const float srr = sums[col * 3 + 1];
        const float sxr = sums[col * 3 + 2];
        term += sxr / (fmaxf(sqrtf(sxx), EPS_F) * fmaxf(sqrtf(srr), EPS_F));
    }
    if (threadIdx.x < CHUNKS) term += rowpart[p * CHUNKS + threadIdx.x];

    #pragma unroll
    for (int m = 32; m > 0; m >>= 1) term += __shfl_down(term, m, 64);
    __shared__ float ws4[4];
    if ((threadIdx.x & 63) == 0) ws4[threadIdx.x >> 6] = term;
    __syncthreads();

    __shared__ bool last;
    if (threadIdx.x == 0) {
        const float total = ws4[0] + ws4[1] + ws4[2] + ws4[3];
        // device-scope publish, then acq_rel counter bump: standard
        // last-block pattern, valid across non-coherent XCD L2s (G16).
        __hip_atomic_store(&planesum[p], total, __ATOMIC_RELEASE,
                           __HIP_MEMORY_SCOPE_AGENT);
        const unsigned int prev = __hip_atomic_fetch_add(
            counter, 1u, __ATOMIC_ACQ_REL, __HIP_MEMORY_SCOPE_AGENT);
        last = (prev == PLANES - 1);
    }
    __syncthreads();

    if (last && threadIdx.x < 64) {
        float v = (threadIdx.x < PLANES)
                      ? __hip_atomic_load(&planesum[threadIdx.x],
                                          __ATOMIC_ACQUIRE,
                                          __HIP_MEMORY_SCOPE_AGENT)
                      : 0.0f;
        #pragma unroll
        for (int m = 32; m > 0; m >>= 1) v += __shfl_down(v, m, 64);
        if (threadIdx.x == 0) out[0] = SCALE * v;
    }
}

extern "C" void kernel_launch(void* const* d_in, const int* in_sizes, int n_in,
                              void* d_out, int out_size, void* d_ws, size_t ws_size,
                              hipStream_t stream) {
    const float* x   = (const float*)d_in[0];
    const float* ref = (const float*)d_in[1];
    float* out = (float*)d_out;

    float* colpart  = (float*)d_ws;                       // 768*1536 floats
    float* rowpart  = colpart + (size_t)NBLK * STATS3;    // 768 floats
    float* planesum = rowpart + NBLK;                     // 48 floats
    unsigned int* counter = (unsigned int*)(planesum + PLANES);  // 1 uint

    spl_main_kernel<<<NBLK, 256, 0, stream>>>(x, ref, colpart, rowpart, counter);
    spl_reduce_kernel<<<PLANES, 256, 0, stream>>>(colpart, rowpart, planesum,
                                                  counter, out);
}